// Round 10
// baseline (306.424 us; speedup 1.0000x reference)
//
#include <hip/hip_runtime.h>
#include <hip/hip_bf16.h>

// AttnBlock: x[4,512,64,64] fp32. GroupNorm(8) -> qkv 1x1conv -> attn -> proj -> +xn
// Q,K,V,P fp8 e4m3. R15 = R14 (transposed-global K/V, conflict-free chunk-major
// LDS, XCD swizzle, R3 2-barrier schedule) + S-phase ILP fix:
//  - S accumulation split into 4 INDEPENDENT MFMA chains (depth 2) + VALU merge.
//    R9 counters showed MfmaUtil 26% with an 8-deep dependent 32x32x64 chain and
//    only 2 waves/SIMD (1 block/CU, LDS-bound) — dependent-latency gaps in the
//    matrix pipe. 4 chains x 2 waves = 8 concurrent chains per SIMD.
//  - setprio hoisted to once per MFMA cluster (was per-instruction).

typedef unsigned short u16;
typedef unsigned char u8;
typedef __bf16 bf16x8 __attribute__((ext_vector_type(8)));
typedef float f32x4 __attribute__((ext_vector_type(4)));
typedef float f32x16 __attribute__((ext_vector_type(16)));
typedef int i32x4 __attribute__((ext_vector_type(4)));
typedef int i32x8 __attribute__((ext_vector_type(8)));
typedef unsigned short u16x4 __attribute__((ext_vector_type(4)));

#define CDIM 512
#define NPOS 4096
#define NBATCH 4

__device__ __forceinline__ u16 f2bf(float x) {
  union { float f; unsigned u; } c; c.f = x;
  unsigned u = c.u;
  u += 0x7fffu + ((u >> 16) & 1u);   // round-to-nearest-even
  return (u16)(u >> 16);
}
__device__ __forceinline__ float bf2f(u16 h) {
  union { unsigned u; float f; } c; c.u = ((unsigned)h) << 16;
  return c.f;
}
// pack 4 floats -> 4 fp8 e4m3 bytes
__device__ __forceinline__ unsigned pk4_fp8(float a, float b, float c, float d) {
  unsigned v = __builtin_amdgcn_cvt_pk_fp8_f32(a, b, 0, false);
  v = __builtin_amdgcn_cvt_pk_fp8_f32(c, d, v, true);
  return v;
}

__device__ __forceinline__ void async16(const u16* g, u16* l) {
  __builtin_amdgcn_global_load_lds(
      (const __attribute__((address_space(1))) unsigned int*)g,
      (__attribute__((address_space(3))) unsigned int*)l, 16, 0, 0);
}
__device__ __forceinline__ void async16b(const u8* g, u8* l) {
  __builtin_amdgcn_global_load_lds(
      (const __attribute__((address_space(1))) unsigned int*)g,
      (__attribute__((address_space(3))) unsigned int*)l, 16, 0, 0);
}

__device__ __forceinline__ void drain_barrier() {
  asm volatile("s_waitcnt vmcnt(0)" ::: "memory");
  __builtin_amdgcn_s_barrier();
}

__device__ __forceinline__ float wred_sum(float v) {
#pragma unroll
  for (int o = 32; o > 0; o >>= 1) v += __shfl_xor(v, o, 64);
  return v;
}

// ---------------- GroupNorm stats: 32 (b,g) groups x 8 slices ----------------
__global__ __launch_bounds__(256) void gn_partial(const float* __restrict__ x,
                                                  float* __restrict__ stats) {
  int gidx = blockIdx.x >> 3;
  int slice = blockIdx.x & 7;
  const float4* src = (const float4*)x + (long)gidx * 65536 + (long)slice * 8192;
  float s = 0.f, ss = 0.f;
  for (int i = threadIdx.x; i < 8192; i += 256) {
    float4 v = src[i];
    s  += v.x + v.y + v.z + v.w;
    ss += v.x * v.x + v.y * v.y + v.z * v.z + v.w * v.w;
  }
  s = wred_sum(s); ss = wred_sum(ss);
  __shared__ float r1[4], r2[4];
  int lane = threadIdx.x & 63, wave = threadIdx.x >> 6;
  if (lane == 0) { r1[wave] = s; r2[wave] = ss; }
  __syncthreads();
  if (threadIdx.x == 0) {
    atomicAdd(&stats[gidx * 2 + 0], r1[0] + r1[1] + r1[2] + r1[3]);
    atomicAdd(&stats[gidx * 2 + 1], r2[0] + r2[1] + r2[2] + r2[3]);
  }
}

// ------- normalize + write xnb bf16 [b,c,p] (residual) and xnT bf16 [b,p,c] -------
__global__ __launch_bounds__(256) void norm_trans(const float* __restrict__ x,
                                                  const float* __restrict__ stats,
                                                  const float* __restrict__ gamma,
                                                  const float* __restrict__ beta,
                                                  u16* __restrict__ xnb,
                                                  u16* __restrict__ xnT) {
  __shared__ float tile[32][33];
  int b = blockIdx.z, c0 = blockIdx.y * 32, p0 = blockIdx.x * 32;
  int g = (b << 3) + (c0 >> 6);
  float cnt = 1.f / 262144.f;
  float mu = stats[g * 2 + 0] * cnt;
  float ms = stats[g * 2 + 1] * cnt;
  float rstd = rsqrtf(ms - mu * mu + 1e-5f);
  int tp = threadIdx.x & 31, tc = threadIdx.x >> 5;
#pragma unroll
  for (int r = 0; r < 4; r++) {
    int cl = tc + r * 8;
    int c = c0 + cl;
    long idx = ((long)(b * CDIM + c)) * NPOS + p0 + tp;
    float v = (x[idx] - mu) * rstd * gamma[c] + beta[c];
    xnb[idx] = f2bf(v);
    tile[cl][tp] = v;
  }
  __syncthreads();
#pragma unroll
  for (int r = 0; r < 4; r++) {
    int pl = tc + r * 8, cl = tp;
    xnT[((long)(b * NPOS + p0 + pl)) * CDIM + c0 + cl] = f2bf(tile[cl][pl]);
  }
}

// ------- fp32 -> bf16 weight convert (wq, wk, wv, wp all [512][512]) -------
__global__ __launch_bounds__(256) void cvt4(const float* __restrict__ a, const float* __restrict__ b,
                                            const float* __restrict__ c, const float* __restrict__ d,
                                            u16* __restrict__ oa, u16* __restrict__ ob,
                                            u16* __restrict__ oc, u16* __restrict__ od) {
  int i = blockIdx.x * 256 + threadIdx.x;
  const float* src; u16* dst;
  switch (blockIdx.y) {
    case 0: src = a; dst = oa; break;
    case 1: src = b; dst = ob; break;
    case 2: src = c; dst = oc; break;
    default: src = d; dst = od; break;
  }
  dst[i] = f2bf(src[i]);
}

// ---------------- gemm_bt: C[m,n] = sum_k A[m,k]*B[n,k]  (both K-contig, bf16) ----------------
// 128(M) x BN tile, BK=64, BN/64*2 waves (wave tile 64x64), XOR-swizzled LDS, dbuf.
// MFMA operands SWAPPED: mfma(bfr, af, acc) -> C/D lane dim = m, reg dim = n.
// MODE 0: fp8 out + bias; gn<512 -> Qf8[gm*512+gn]; gn>=512 -> KT[b][c'/16][p][16B]
//         (Cp = Qf8 base; KT = Cp + 8388608; b=gm>>12, p=gm&4095, c'=gn-512)
// MODE 5: fp8 out + bias[m]; VT[b][gn/16][gm][16B]  (Cp = VT base, z = batch)
// MODE 6: f32  out = acc + bias[m] + bf16 resid              (proj + residual)
template <int MODE, int BN>
__global__ __launch_bounds__(BN * 2, 2) void gemm_bt(
    const u16* __restrict__ A, const u16* __restrict__ B,
    void* __restrict__ Cp, const float* __restrict__ bias,
    const float* __restrict__ bias1, const u16* __restrict__ residb,
    int N, int K, int lda, int ldb,
    long sA, long sB, long sC, long sR) {
  __shared__ u16 Asm[2][128 * 64];
  __shared__ u16 Bsm[2][BN * 64];
  constexpr int NT = BN * 2;       // threads
  constexpr int STEP = NT / 8;     // staging rows per round
  int bz = blockIdx.z;
  A += (long)bz * sA;
  B += (long)bz * sB;
  int bm = blockIdx.y, bn = blockIdx.x;
  int tid = threadIdx.x;
  int lane = tid & 63, wave = tid >> 6;
  int wm = (wave & 1) * 64, wn = (wave >> 1) * 64;

  int row0 = tid >> 3;             // 0..STEP-1
  int ko = (tid & 7) * 8;
  int kos = ko ^ ((row0 & 7) * 8); // STEP multiple of 8 -> row&7 invariant
  f32x4 acc[4][4] = {};
  int row16 = lane & 15;
  int kq = (lane >> 4) * 8;

  auto stage = [&](int buf, int k0) {
#pragma unroll
    for (int r = 0; r < 128 / STEP; r++) {
      int row = row0 + r * STEP;
      async16(A + (long)(bm * 128 + row) * lda + k0 + kos, &Asm[buf][row * 64 + ko]);
    }
#pragma unroll
    for (int r = 0; r < BN / STEP; r++) {
      int row = row0 + r * STEP;
      async16(B + (long)(bn * BN + row) * ldb + k0 + kos, &Bsm[buf][row * 64 + ko]);
    }
  };

  stage(0, 0);
  drain_barrier();
  int cur = 0;
  for (int k0 = 0; k0 < K; k0 += 64) {
    if (k0 + 64 < K) stage(cur ^ 1, k0 + 64);   // prefetch next tile
#pragma unroll
    for (int s2 = 0; s2 < 2; s2++) {
      bf16x8 af[4], bfr[4];
#pragma unroll
      for (int i = 0; i < 4; i++) {
        int row = wm + i * 16 + row16;
        af[i] = *(const bf16x8*)&Asm[cur][row * 64 + ((s2 * 32 + kq) ^ ((row & 7) * 8))];
      }
#pragma unroll
      for (int j = 0; j < 4; j++) {
        int row = wn + j * 16 + row16;
        bfr[j] = *(const bf16x8*)&Bsm[cur][row * 64 + ((s2 * 32 + kq) ^ ((row & 7) * 8))];
      }
      __builtin_amdgcn_s_setprio(1);
#pragma unroll
      for (int i = 0; i < 4; i++)
#pragma unroll
        for (int j = 0; j < 4; j++)
          acc[i][j] = __builtin_amdgcn_mfma_f32_16x16x32_bf16(bfr[j], af[i], acc[i][j], 0, 0, 0);
      __builtin_amdgcn_s_setprio(0);
    }
    drain_barrier();
    cur ^= 1;
  }

  // epilogue (swapped layout): m = lane&15 within tile, n = (lane>>4)*4 + reg
  int mcol = lane & 15, rb = (lane >> 4) * 4;
  long zC = (long)bz * sC;
#pragma unroll
  for (int i = 0; i < 4; i++) {
    int gm = bm * 128 + wm + i * 16 + mcol;
    float bm_add = 0.f;
    if constexpr (MODE == 5 || MODE == 6) bm_add = bias[gm];
#pragma unroll
    for (int j = 0; j < 4; j++) {
      int gn0 = bn * BN + wn + j * 16 + rb;
      float v[4];
#pragma unroll
      for (int r = 0; r < 4; r++) v[r] = acc[i][j][r];
      if constexpr (MODE == 0) {
        const float* bb = (gn0 < 512) ? (bias + gn0) : (bias1 + (gn0 - 512));
#pragma unroll
        for (int r = 0; r < 4; r++) v[r] += bb[r];
        unsigned pk = pk4_fp8(v[0], v[1], v[2], v[3]);
        if (gn0 < 512) {
          *(unsigned*)&((u8*)Cp)[(long)gm * 512 + gn0] = pk;
        } else {
          int b = gm >> 12, p = gm & 4095, c = gn0 - 512;
          *(unsigned*)&((u8*)Cp)[8388608L + (long)b * 2097152 +
                                 (long)(c >> 4) * 65536 + p * 16 + (c & 15)] = pk;
        }
      }
      if constexpr (MODE == 5) {
#pragma unroll
        for (int r = 0; r < 4; r++) v[r] += bm_add;
        unsigned pk = pk4_fp8(v[0], v[1], v[2], v[3]);
        *(unsigned*)&((u8*)Cp)[(long)bz * 2097152 + (long)(gn0 >> 4) * 8192 +
                               gm * 16 + (gn0 & 15)] = pk;
      }
      if constexpr (MODE == 6) {
        long off = zC + (long)gm * N + gn0;
        u16x4 rv = *(const u16x4*)&residb[(long)bz * sR + (long)gm * N + gn0];
        f32x4 o;
#pragma unroll
        for (int r = 0; r < 4; r++) o[r] = v[r] + bm_add + bf2f(rv[r]);
        *(f32x4*)&((float*)Cp)[off] = o;
      }
    }
  }
}

// ---------------- fattn: fused S=exp(QK^T*scale) and H=(S.V)/rowsum ----------------
// 256 blocks (XCD-swizzled: 2 XCDs per batch), 512 thr (8 waves: wi=w>>2, wj=w&3).
// i-tile 64, j-step 128, 32 steps. MX-fp8 MFMA 32x32x64, swapped operands
// (D lane=m(l31), reg n=(r&3)+8*(r>>2)+4*h; A/B frag: lane=row, k-bytes h*32..+31).
// CHUNK-MAJOR LDS (R9-verified conflict-free) from TRANSPOSED global buffers.
// S-phase: 4 independent accumulation chains (depth 2) + merge — fills the MFMA
// pipe at 2 waves/SIMD (R9: 8-deep chain left MfmaUtil at 26%).
// Per step (R3 schedule): syncA; stageV(t); S=Q.K (8 MFMA); exp2 -> P + rowsum;
// syncB; stageK(t+1); acc += P.V^T (8 MFMA). Epilogue: lsum reduce, H=(PV)/l bf16.
__global__ __launch_bounds__(512, 1) void fattn(const u8* __restrict__ Qf8,
                                                const u8* __restrict__ VT,
                                                u16* __restrict__ H, float scale2) {
  __shared__ u8 Ksm[65536];      // 32 ch-planes x 128 j x 16B
  __shared__ u8 Vsm[65536];      // 8 jc-planes x 512 c x 16B
  __shared__ u8 Pp[8192];        // 8 jc-planes x 64 i x 16B
  __shared__ float lsum[4][64];
  int tid = threadIdx.x, lane = tid & 63, w = tid >> 6;
  int l31 = lane & 31, h = lane >> 5;
  int wi = w >> 2, wj = w & 3;
  // XCD swizzle (R7-verified): round-robin dispatch -> xcd = lid&7; 2 XCDs/batch.
  int lid = blockIdx.x + 64 * blockIdx.z;
  int xcd = lid & 7, slot = lid >> 3;
  int bz = xcd >> 1;
  int bm = (xcd & 1) * 32 + slot;
  const u8* Qb  = Qf8 + (long)bz * 2097152;            // [4096 p][512 c]
  const u8* KTb = Qf8 + 8388608 + (long)bz * 2097152;  // [32 ch][4096 p][16B]
  const u8* VTb = VT + (long)bz * 2097152;             // [256 jc][512 c][16B]

  // Q rows (bm*64 + wi*32 + l31), full c=512, resident in regs (64 VGPR)
  i32x8 qf[8];
  {
    const u8* qrow = Qb + (long)(bm * 64 + wi * 32 + l31) * 512 + h * 32;
#pragma unroll
    for (int s = 0; s < 8; s++) {
      i32x4 lo = *(const i32x4*)(qrow + s * 64);
      i32x4 hi = *(const i32x4*)(qrow + s * 64 + 16);
      qf[s] = __builtin_shufflevector(lo, hi, 0, 1, 2, 3, 4, 5, 6, 7);
    }
  }

  // stage K(t): zz -> ch = zz>>7, j = zz&127; LDS linear; global contiguous in j
  auto stageK = [&](int t) {
#pragma unroll
    for (int r = 0; r < 8; r++) {
      int zz = tid + r * 512;
      int ch = zz >> 7, j = zz & 127;
      async16b(KTb + (long)ch * 65536 + (t * 128 + j) * 16, &Ksm[zz * 16]);
    }
  };
  // stage V(t): zz -> jc = zz>>9, c = zz&511; global contiguous in c
  auto stageV = [&](int t) {
#pragma unroll
    for (int r = 0; r < 8; r++) {
      int zz = tid + r * 512;
      int jc = zz >> 9, c = zz & 511;
      async16b(VTb + (long)(t * 8 + jc) * 8192 + c * 16, &Vsm[zz * 16]);
    }
  };

  f32x16 acc[2][2] = {};   // [i-sub][c-sub]; wave c-base = w*64
  float rsum = 0.f;
  int i = wi * 32 + l31;   // this wave's S row (lane)
  int jr = wj * 32 + l31;  // this wave's K row (lane)

  stageK(0);

  for (int t = 0; t < 32; t++) {
    __syncthreads();              // A: K(t) staged+drained; Vsm/Pp reads of t-1 done
    stageV(t);
    // ---- phase 1: S = Q.K^T over c=512; 4 independent chains (depth 2) ----
    f32x16 s4[4] = {};
    __builtin_amdgcn_s_setprio(1);
#pragma unroll
    for (int s = 0; s < 8; s++) {
      int a0 = (4 * s + 2 * h) * 2048 + jr * 16;
      i32x4 lo = *(const i32x4*)&Ksm[a0];
      i32x4 hi = *(const i32x4*)&Ksm[a0 + 2048];
      i32x8 bfk = __builtin_shufflevector(lo, hi, 0, 1, 2, 3, 4, 5, 6, 7);
      s4[s & 3] = __builtin_amdgcn_mfma_scale_f32_32x32x64_f8f6f4(
          bfk, qf[s], s4[s & 3], 0, 0, 0, 0x7F7F7F7F, 0, 0x7F7F7F7F);
    }
    __builtin_amdgcn_s_setprio(0);
    // merge chains + exp2 + rowsum + pack P -> Pp chunk-major
    {
      float pv[16];
      float rs = 0.f;
#pragma unroll
      for (int r = 0; r < 16; r++) {
        float sv = (s4[0][r] + s4[1][r]) + (s4[2][r] + s4[3][r]);
        pv[r] = exp2f(sv * scale2);
        rs += pv[r];
      }
      rsum += rs + __shfl_xor(rs, 32, 64);
#pragma unroll
      for (int g = 0; g < 4; g++) {
        int jc = wj * 2 + (g >> 1);
        *(unsigned*)&Pp[jc * 1024 + i * 16 + 8 * (g & 1) + 4 * h] =
            pk4_fp8(pv[4 * g], pv[4 * g + 1], pv[4 * g + 2], pv[4 * g + 3]);
      }
    }
    __syncthreads();              // B: V(t) staged+drained; Pp writes visible
    if (t < 31) stageK(t + 1);
    // ---- phase 2: acc += P.V^T over local j=128 (2 k-steps, 4 indep accs) ----
#pragma unroll
    for (int kk = 0; kk < 2; kk++) {
      int kb = 4 * kk + 2 * h;
      i32x8 afp[2], bfv[2];
#pragma unroll
      for (int mr = 0; mr < 2; mr++) {
        int ii = mr * 32 + l31;
        i32x4 lo = *(const i32x4*)&Pp[kb * 1024 + ii * 16];
        i32x4 hi = *(const i32x4*)&Pp[(kb + 1) * 1024 + ii * 16];
        afp[mr] = __builtin_shufflevector(lo, hi, 0, 1, 2, 3, 4, 5, 6, 7);
      }
#pragma unroll
      for (int nr = 0; nr < 2; nr++) {
        int c = w * 64 + nr * 32 + l31;
        i32x4 lo = *(const i32x4*)&Vsm[kb * 8192 + c * 16];
        i32x4 hi = *(const i32x4*)&Vsm[(kb + 1) * 8192 + c * 16];
        bfv[nr] = __builtin_shufflevector(lo, hi, 0, 1, 2, 3, 4, 5, 6, 7);
      }
      __builtin_amdgcn_s_setprio(1);
#pragma unroll
      for (int mr = 0; mr < 2; mr++)
#pragma unroll
        for (int nr = 0; nr < 2; nr++)
          acc[mr][nr] = __builtin_amdgcn_mfma_scale_f32_32x32x64_f8f6f4(
              bfv[nr], afp[mr], acc[mr][nr], 0, 0, 0, 0x7F7F7F7F, 0, 0x7F7F7F7F);
      __builtin_amdgcn_s_setprio(0);
    }
  }

  // ---- epilogue: reduce rowsums across wj, divide, store H bf16 ----
  if (lane < 32) lsum[wj][wi * 32 + l31] = rsum;
  __syncthreads();
#pragma unroll
  for (int mr = 0; mr < 2; mr++) {
    int li = mr * 32 + l31;
    float lt = lsum[0][li] + lsum[1][li] + lsum[2][li] + lsum[3][li];
    float inv = 1.f / lt;
    long hrow = ((long)bz * NPOS + bm * 64 + li) * 512;
#pragma unroll
    for (int nr = 0; nr < 2; nr++) {
#pragma unroll
      for (int g = 0; g < 4; g++) {
        u16x4 o;
#pragma unroll
        for (int r = 0; r < 4; r++) o[r] = f2bf(acc[mr][nr][4 * g + r] * inv);
        *(u16x4*)&H[hrow + w * 64 + nr * 32 + 8 * g + 4 * h] = o;
      }
    }
  }
}

extern "C" void kernel_launch(void* const* d_in, const int* in_sizes, int n_in,
                              void* d_out, int out_size, void* d_ws, size_t ws_size,
                              hipStream_t stream) {
  const float* x     = (const float*)d_in[0];
  const float* gamma = (const float*)d_in[1];
  const float* beta  = (const float*)d_in[2];
  const float* wq = (const float*)d_in[3];
  const float* bq = (const float*)d_in[4];
  const float* wk = (const float*)d_in[5];
  const float* bk = (const float*)d_in[6];
  const float* wv = (const float*)d_in[7];
  const float* bv = (const float*)d_in[8];
  const float* wp = (const float*)d_in[9];
  const float* bp = (const float*)d_in[10];
  float* out = (float*)d_out;

  // workspace layout (bytes)
  char* W = (char*)d_ws;
  float* stats = (float*)(W + 0);               // 256 B
  u16* xnb  = (u16*)(W + 65792);                // 16,777,216 bf16 [b,c,p] residual
  u16* xnT  = (u16*)(W + 16843008);             // 16,777,216 bf16 [b,p,c]
  u16* wqkb = (u16*)(W + 33620224);             // 1,048,576  bf16 [1024(cq;ck)][512]
  u16* wvb  = (u16*)(W + 34668800);             // 524,288    bf16 [512][512]
  u16* wpb  = (u16*)(W + 35193088);             // 524,288    bf16 [512][512]
  u8*  QKf8 = (u8*)(W + 37290240);              // 16,777,216: Qf8 [b,p,512] | KT [b,32,4096,16]
  u8*  VT   = (u8*)(W + 54067456);              // 8,388,608 fp8 VT [b,256,512,16]
  u16* Hws  = (u16*)(W + 62456064);             // 16,777,216 bf16 [b,i,512]
  (void)in_sizes; (void)n_in; (void)out_size; (void)ws_size;

  hipMemsetAsync(W, 0, 256, stream);   // stats
  gn_partial<<<256, 256, 0, stream>>>(x, stats);
  norm_trans<<<dim3(128, 16, 4), 256, 0, stream>>>(x, stats, gamma, beta, xnb, xnT);
  cvt4<<<dim3(1024, 4), 256, 0, stream>>>(wq, wk, wv, wp, wqkb, wqkb + 262144, wvb, wpb);

  const long NC = (long)NPOS * CDIM;    // 2,097,152
  const long CN = (long)CDIM * NPOS;
  const float scale = 0.044194173824159216f;        // 1/sqrt(512)
  const float scale2 = scale * 1.4426950408889634f; // 1/sqrt(512) * log2(e)

  // QK proj: A=xnT (M=16384), B=wqkb (N=1024), K=512. Q -> Qf8 rows, K -> KT planes.
  gemm_bt<0, 128><<<dim3(8, 128, 1), 256, 0, stream>>>(xnT, wqkb, QKf8, bq, bk, nullptr,
      1024, CDIM, CDIM, CDIM, 0, 0, 0, 0);
  // V proj: per batch M=512(c), N=4096(p), K=512 -> VT[b][p/16][c][16B]
  gemm_bt<5, 128><<<dim3(32, 4, 4), 256, 0, stream>>>(wvb, xnT, VT, bv, nullptr, nullptr,
      NPOS, CDIM, CDIM, CDIM, 0, NC, 0, 0);
  // fused attention: H[b,i,512] = softmax(Q.K^T/sqrt(c)) . V
  fattn<<<dim3(64, 1, NBATCH), 512, 0, stream>>>(QKf8, VT, Hws, scale2);
  // out[b][c, p] = wp . H_b^T + bp + xnb  (M=512, N=4096, K=512)
  gemm_bt<6, 128><<<dim3(32, 4, 4), 256, 0, stream>>>(wpb, Hws, (void*)out, bp, nullptr, xnb,
      NPOS, CDIM, CDIM, CDIM, 0, (long)NPOS * CDIM, CN, CN);
}

// Round 11
// 282.333 us; speedup vs baseline: 1.0853x; 1.0853x over previous
//
#include <hip/hip_runtime.h>
#include <hip/hip_bf16.h>

// AttnBlock: x[4,512,64,64] fp32. GroupNorm(8) -> qkv 1x1conv -> attn -> proj -> +xn
// Q,K,V,P fp8 e4m3. R16 = R14/R9 (best total, 280us: transposed-global K/V,
// conflict-free chunk-major LDS fattn, XCD swizzle, R3 2-barrier schedule,
// single-chain S) with R10's ILP experiment REVERTED (regressed -21us), plus
// G13 vectorization of the two scalar memory kernels:
//  - norm_trans: 64x64 tile, float4 loads (16B/lane), u16x4 xnb stores,
//    LDS transpose (65-pad), u16x8 (16B) xnT stores.
//  - cvt4: float4 -> u16x4 (1/4 threads).

typedef unsigned short u16;
typedef unsigned char u8;
typedef __bf16 bf16x8 __attribute__((ext_vector_type(8)));
typedef float f32x4 __attribute__((ext_vector_type(4)));
typedef float f32x16 __attribute__((ext_vector_type(16)));
typedef int i32x4 __attribute__((ext_vector_type(4)));
typedef int i32x8 __attribute__((ext_vector_type(8)));
typedef unsigned short u16x4 __attribute__((ext_vector_type(4)));
typedef unsigned short u16x8 __attribute__((ext_vector_type(8)));

#define CDIM 512
#define NPOS 4096
#define NBATCH 4

__device__ __forceinline__ u16 f2bf(float x) {
  union { float f; unsigned u; } c; c.f = x;
  unsigned u = c.u;
  u += 0x7fffu + ((u >> 16) & 1u);   // round-to-nearest-even
  return (u16)(u >> 16);
}
__device__ __forceinline__ float bf2f(u16 h) {
  union { unsigned u; float f; } c; c.u = ((unsigned)h) << 16;
  return c.f;
}
// pack 4 floats -> 4 fp8 e4m3 bytes
__device__ __forceinline__ unsigned pk4_fp8(float a, float b, float c, float d) {
  unsigned v = __builtin_amdgcn_cvt_pk_fp8_f32(a, b, 0, false);
  v = __builtin_amdgcn_cvt_pk_fp8_f32(c, d, v, true);
  return v;
}

__device__ __forceinline__ void async16(const u16* g, u16* l) {
  __builtin_amdgcn_global_load_lds(
      (const __attribute__((address_space(1))) unsigned int*)g,
      (__attribute__((address_space(3))) unsigned int*)l, 16, 0, 0);
}
__device__ __forceinline__ void async16b(const u8* g, u8* l) {
  __builtin_amdgcn_global_load_lds(
      (const __attribute__((address_space(1))) unsigned int*)g,
      (__attribute__((address_space(3))) unsigned int*)l, 16, 0, 0);
}

__device__ __forceinline__ void drain_barrier() {
  asm volatile("s_waitcnt vmcnt(0)" ::: "memory");
  __builtin_amdgcn_s_barrier();
}

__device__ __forceinline__ float wred_sum(float v) {
#pragma unroll
  for (int o = 32; o > 0; o >>= 1) v += __shfl_xor(v, o, 64);
  return v;
}

// ---------------- GroupNorm stats: 32 (b,g) groups x 8 slices ----------------
__global__ __launch_bounds__(256) void gn_partial(const float* __restrict__ x,
                                                  float* __restrict__ stats) {
  int gidx = blockIdx.x >> 3;
  int slice = blockIdx.x & 7;
  const float4* src = (const float4*)x + (long)gidx * 65536 + (long)slice * 8192;
  float s = 0.f, ss = 0.f;
  for (int i = threadIdx.x; i < 8192; i += 256) {
    float4 v = src[i];
    s  += v.x + v.y + v.z + v.w;
    ss += v.x * v.x + v.y * v.y + v.z * v.z + v.w * v.w;
  }
  s = wred_sum(s); ss = wred_sum(ss);
  __shared__ float r1[4], r2[4];
  int lane = threadIdx.x & 63, wave = threadIdx.x >> 6;
  if (lane == 0) { r1[wave] = s; r2[wave] = ss; }
  __syncthreads();
  if (threadIdx.x == 0) {
    atomicAdd(&stats[gidx * 2 + 0], r1[0] + r1[1] + r1[2] + r1[3]);
    atomicAdd(&stats[gidx * 2 + 1], r2[0] + r2[1] + r2[2] + r2[3]);
  }
}

// ------- normalize + write xnb bf16 [b,c,p] (residual) and xnT bf16 [b,p,c] -------
// 64c x 64p tile, vectorized: float4 loads, u16x4 xnb stores, u16x8 xnT stores.
__global__ __launch_bounds__(256) void norm_trans(const float* __restrict__ x,
                                                  const float* __restrict__ stats,
                                                  const float* __restrict__ gamma,
                                                  const float* __restrict__ beta,
                                                  u16* __restrict__ xnb,
                                                  u16* __restrict__ xnT) {
  __shared__ float tile[64][65];
  int b = blockIdx.z, c0 = blockIdx.y * 64, p0 = blockIdx.x * 64;
  int g = (b << 3) + (c0 >> 6);
  float cnt = 1.f / 262144.f;
  float mu = stats[g * 2 + 0] * cnt;
  float ms = stats[g * 2 + 1] * cnt;
  float rstd = rsqrtf(ms - mu * mu + 1e-5f);
  int tq = threadIdx.x & 3, cl = threadIdx.x >> 2;   // cl: 0..63 (c row)
  int c = c0 + cl;
  float ga = gamma[c] * rstd, be = beta[c] - mu * ga;   // n = v*ga + be
  long rowb = ((long)(b * CDIM + c)) * NPOS + p0;
#pragma unroll
  for (int k = 0; k < 4; k++) {
    int pl = tq * 4 + k * 16;
    float4 v = *(const float4*)&x[rowb + pl];
    float4 n;
    n.x = v.x * ga + be; n.y = v.y * ga + be;
    n.z = v.z * ga + be; n.w = v.w * ga + be;
    u16x4 o; o[0] = f2bf(n.x); o[1] = f2bf(n.y); o[2] = f2bf(n.z); o[3] = f2bf(n.w);
    *(u16x4*)&xnb[rowb + pl] = o;
    tile[cl][pl] = n.x; tile[cl][pl + 1] = n.y;
    tile[cl][pl + 2] = n.z; tile[cl][pl + 3] = n.w;
  }
  __syncthreads();
  int pl = threadIdx.x >> 2;                          // p row 0..63
  long colb = ((long)(b * NPOS + p0 + pl)) * CDIM + c0;
#pragma unroll
  for (int s = 0; s < 2; s++) {
    int cc0 = (tq + 4 * s) * 8;
    u16x8 o;
#pragma unroll
    for (int e = 0; e < 8; e++) o[e] = f2bf(tile[cc0 + e][pl]);
    *(u16x8*)&xnT[colb + cc0] = o;
  }
}

// ------- fp32 -> bf16 weight convert (wq, wk, wv, wp all [512][512]), float4 -------
__global__ __launch_bounds__(256) void cvt4(const float* __restrict__ a, const float* __restrict__ b,
                                            const float* __restrict__ c, const float* __restrict__ d,
                                            u16* __restrict__ oa, u16* __restrict__ ob,
                                            u16* __restrict__ oc, u16* __restrict__ od) {
  int i = (blockIdx.x * 256 + threadIdx.x) * 4;
  const float* src; u16* dst;
  switch (blockIdx.y) {
    case 0: src = a; dst = oa; break;
    case 1: src = b; dst = ob; break;
    case 2: src = c; dst = oc; break;
    default: src = d; dst = od; break;
  }
  float4 v = *(const float4*)&src[i];
  u16x4 o; o[0] = f2bf(v.x); o[1] = f2bf(v.y); o[2] = f2bf(v.z); o[3] = f2bf(v.w);
  *(u16x4*)&dst[i] = o;
}

// ---------------- gemm_bt: C[m,n] = sum_k A[m,k]*B[n,k]  (both K-contig, bf16) ----------------
// 128(M) x BN tile, BK=64, BN/64*2 waves (wave tile 64x64), XOR-swizzled LDS, dbuf.
// MFMA operands SWAPPED: mfma(bfr, af, acc) -> C/D lane dim = m, reg dim = n.
// MODE 0: fp8 out + bias; gn<512 -> Qf8[gm*512+gn]; gn>=512 -> KT[b][c'/16][p][16B]
//         (Cp = Qf8 base; KT = Cp + 8388608; b=gm>>12, p=gm&4095, c'=gn-512)
// MODE 5: fp8 out + bias[m]; VT[b][gn/16][gm][16B]  (Cp = VT base, z = batch)
// MODE 6: f32  out = acc + bias[m] + bf16 resid              (proj + residual)
template <int MODE, int BN>
__global__ __launch_bounds__(BN * 2, 2) void gemm_bt(
    const u16* __restrict__ A, const u16* __restrict__ B,
    void* __restrict__ Cp, const float* __restrict__ bias,
    const float* __restrict__ bias1, const u16* __restrict__ residb,
    int N, int K, int lda, int ldb,
    long sA, long sB, long sC, long sR) {
  __shared__ u16 Asm[2][128 * 64];
  __shared__ u16 Bsm[2][BN * 64];
  constexpr int NT = BN * 2;       // threads
  constexpr int STEP = NT / 8;     // staging rows per round
  int bz = blockIdx.z;
  A += (long)bz * sA;
  B += (long)bz * sB;
  int bm = blockIdx.y, bn = blockIdx.x;
  int tid = threadIdx.x;
  int lane = tid & 63, wave = tid >> 6;
  int wm = (wave & 1) * 64, wn = (wave >> 1) * 64;

  int row0 = tid >> 3;             // 0..STEP-1
  int ko = (tid & 7) * 8;
  int kos = ko ^ ((row0 & 7) * 8); // STEP multiple of 8 -> row&7 invariant
  f32x4 acc[4][4] = {};
  int row16 = lane & 15;
  int kq = (lane >> 4) * 8;

  auto stage = [&](int buf, int k0) {
#pragma unroll
    for (int r = 0; r < 128 / STEP; r++) {
      int row = row0 + r * STEP;
      async16(A + (long)(bm * 128 + row) * lda + k0 + kos, &Asm[buf][row * 64 + ko]);
    }
#pragma unroll
    for (int r = 0; r < BN / STEP; r++) {
      int row = row0 + r * STEP;
      async16(B + (long)(bn * BN + row) * ldb + k0 + kos, &Bsm[buf][row * 64 + ko]);
    }
  };

  stage(0, 0);
  drain_barrier();
  int cur = 0;
  for (int k0 = 0; k0 < K; k0 += 64) {
    if (k0 + 64 < K) stage(cur ^ 1, k0 + 64);   // prefetch next tile
#pragma unroll
    for (int s2 = 0; s2 < 2; s2++) {
      bf16x8 af[4], bfr[4];
#pragma unroll
      for (int i = 0; i < 4; i++) {
        int row = wm + i * 16 + row16;
        af[i] = *(const bf16x8*)&Asm[cur][row * 64 + ((s2 * 32 + kq) ^ ((row & 7) * 8))];
      }
#pragma unroll
      for (int j = 0; j < 4; j++) {
        int row = wn + j * 16 + row16;
        bfr[j] = *(const bf16x8*)&Bsm[cur][row * 64 + ((s2 * 32 + kq) ^ ((row & 7) * 8))];
      }
      __builtin_amdgcn_s_setprio(1);
#pragma unroll
      for (int i = 0; i < 4; i++)
#pragma unroll
        for (int j = 0; j < 4; j++)
          acc[i][j] = __builtin_amdgcn_mfma_f32_16x16x32_bf16(bfr[j], af[i], acc[i][j], 0, 0, 0);
      __builtin_amdgcn_s_setprio(0);
    }
    drain_barrier();
    cur ^= 1;
  }

  // epilogue (swapped layout): m = lane&15 within tile, n = (lane>>4)*4 + reg
  int mcol = lane & 15, rb = (lane >> 4) * 4;
  long zC = (long)bz * sC;
#pragma unroll
  for (int i = 0; i < 4; i++) {
    int gm = bm * 128 + wm + i * 16 + mcol;
    float bm_add = 0.f;
    if constexpr (MODE == 5 || MODE == 6) bm_add = bias[gm];
#pragma unroll
    for (int j = 0; j < 4; j++) {
      int gn0 = bn * BN + wn + j * 16 + rb;
      float v[4];
#pragma unroll
      for (int r = 0; r < 4; r++) v[r] = acc[i][j][r];
      if constexpr (MODE == 0) {
        const float* bb = (gn0 < 512) ? (bias + gn0) : (bias1 + (gn0 - 512));
#pragma unroll
        for (int r = 0; r < 4; r++) v[r] += bb[r];
        unsigned pk = pk4_fp8(v[0], v[1], v[2], v[3]);
        if (gn0 < 512) {
          *(unsigned*)&((u8*)Cp)[(long)gm * 512 + gn0] = pk;
        } else {
          int b = gm >> 12, p = gm & 4095, c = gn0 - 512;
          *(unsigned*)&((u8*)Cp)[8388608L + (long)b * 2097152 +
                                 (long)(c >> 4) * 65536 + p * 16 + (c & 15)] = pk;
        }
      }
      if constexpr (MODE == 5) {
#pragma unroll
        for (int r = 0; r < 4; r++) v[r] += bm_add;
        unsigned pk = pk4_fp8(v[0], v[1], v[2], v[3]);
        *(unsigned*)&((u8*)Cp)[(long)bz * 2097152 + (long)(gn0 >> 4) * 8192 +
                               gm * 16 + (gn0 & 15)] = pk;
      }
      if constexpr (MODE == 6) {
        long off = zC + (long)gm * N + gn0;
        u16x4 rv = *(const u16x4*)&residb[(long)bz * sR + (long)gm * N + gn0];
        f32x4 o;
#pragma unroll
        for (int r = 0; r < 4; r++) o[r] = v[r] + bm_add + bf2f(rv[r]);
        *(f32x4*)&((float*)Cp)[off] = o;
      }
    }
  }
}

// ---------------- fattn: fused S=exp(QK^T*scale) and H=(S.V)/rowsum ----------------
// 256 blocks (XCD-swizzled: 2 XCDs per batch), 512 thr (8 waves: wi=w>>2, wj=w&3).
// i-tile 64, j-step 128, 32 steps. MX-fp8 MFMA 32x32x64, swapped operands
// (D lane=m(l31), reg n=(r&3)+8*(r>>2)+4*h; A/B frag: lane=row, k-bytes h*32..+31).
// CHUNK-MAJOR LDS (R9-verified conflict-free) from TRANSPOSED global buffers.
// Per step (R3 schedule): syncA; stageV(t); S=Q.K (8 MFMA); exp2 -> P + rowsum;
// syncB; stageK(t+1); acc += P.V^T (8 MFMA). Epilogue: lsum reduce, H=(PV)/l bf16.
__global__ __launch_bounds__(512, 1) void fattn(const u8* __restrict__ Qf8,
                                                const u8* __restrict__ VT,
                                                u16* __restrict__ H, float scale2) {
  __shared__ u8 Ksm[65536];      // 32 ch-planes x 128 j x 16B
  __shared__ u8 Vsm[65536];      // 8 jc-planes x 512 c x 16B
  __shared__ u8 Pp[8192];        // 8 jc-planes x 64 i x 16B
  __shared__ float lsum[4][64];
  int tid = threadIdx.x, lane = tid & 63, w = tid >> 6;
  int l31 = lane & 31, h = lane >> 5;
  int wi = w >> 2, wj = w & 3;
  // XCD swizzle (R7-verified): round-robin dispatch -> xcd = lid&7; 2 XCDs/batch.
  int lid = blockIdx.x + 64 * blockIdx.z;
  int xcd = lid & 7, slot = lid >> 3;
  int bz = xcd >> 1;
  int bm = (xcd & 1) * 32 + slot;
  const u8* Qb  = Qf8 + (long)bz * 2097152;            // [4096 p][512 c]
  const u8* KTb = Qf8 + 8388608 + (long)bz * 2097152;  // [32 ch][4096 p][16B]
  const u8* VTb = VT + (long)bz * 2097152;             // [256 jc][512 c][16B]

  // Q rows (bm*64 + wi*32 + l31), full c=512, resident in regs (64 VGPR)
  i32x8 qf[8];
  {
    const u8* qrow = Qb + (long)(bm * 64 + wi * 32 + l31) * 512 + h * 32;
#pragma unroll
    for (int s = 0; s < 8; s++) {
      i32x4 lo = *(const i32x4*)(qrow + s * 64);
      i32x4 hi = *(const i32x4*)(qrow + s * 64 + 16);
      qf[s] = __builtin_shufflevector(lo, hi, 0, 1, 2, 3, 4, 5, 6, 7);
    }
  }

  // stage K(t): zz -> ch = zz>>7, j = zz&127; LDS linear; global contiguous in j
  auto stageK = [&](int t) {
#pragma unroll
    for (int r = 0; r < 8; r++) {
      int zz = tid + r * 512;
      int ch = zz >> 7, j = zz & 127;
      async16b(KTb + (long)ch * 65536 + (t * 128 + j) * 16, &Ksm[zz * 16]);
    }
  };
  // stage V(t): zz -> jc = zz>>9, c = zz&511; global contiguous in c
  auto stageV = [&](int t) {
#pragma unroll
    for (int r = 0; r < 8; r++) {
      int zz = tid + r * 512;
      int jc = zz >> 9, c = zz & 511;
      async16b(VTb + (long)(t * 8 + jc) * 8192 + c * 16, &Vsm[zz * 16]);
    }
  };

  f32x16 acc[2][2] = {};   // [i-sub][c-sub]; wave c-base = w*64
  float rsum = 0.f;
  int i = wi * 32 + l31;   // this wave's S row (lane)
  int jr = wj * 32 + l31;  // this wave's K row (lane)

  stageK(0);

  for (int t = 0; t < 32; t++) {
    __syncthreads();              // A: K(t) staged+drained; Vsm/Pp reads of t-1 done
    stageV(t);
    // ---- phase 1: S = Q.K^T over c=512 (8 MFMA, regs + Ksm) ----
    f32x16 s16 = {};
#pragma unroll
    for (int s = 0; s < 8; s++) {
      int a0 = (4 * s + 2 * h) * 2048 + jr * 16;
      i32x4 lo = *(const i32x4*)&Ksm[a0];
      i32x4 hi = *(const i32x4*)&Ksm[a0 + 2048];
      i32x8 bfk = __builtin_shufflevector(lo, hi, 0, 1, 2, 3, 4, 5, 6, 7);
      __builtin_amdgcn_s_setprio(1);
      s16 = __builtin_amdgcn_mfma_scale_f32_32x32x64_f8f6f4(
          bfk, qf[s], s16, 0, 0, 0, 0x7F7F7F7F, 0, 0x7F7F7F7F);
      __builtin_amdgcn_s_setprio(0);
    }
    // exp2 + rowsum + pack P -> Pp chunk-major (reg r: j = wj*32+(r&3)+8*(r>>2)+4h)
    {
      float pv[16];
      float rs = 0.f;
#pragma unroll
      for (int r = 0; r < 16; r++) { pv[r] = exp2f(s16[r] * scale2); rs += pv[r]; }
      rsum += rs + __shfl_xor(rs, 32, 64);
#pragma unroll
      for (int g = 0; g < 4; g++) {
        int jc = wj * 2 + (g >> 1);
        *(unsigned*)&Pp[jc * 1024 + i * 16 + 8 * (g & 1) + 4 * h] =
            pk4_fp8(pv[4 * g], pv[4 * g + 1], pv[4 * g + 2], pv[4 * g + 3]);
      }
    }
    __syncthreads();              // B: V(t) staged+drained; Pp writes visible
    if (t < 31) stageK(t + 1);
    // ---- phase 2: acc += P.V^T over local j=128 (2 MFMA k-steps) ----
#pragma unroll
    for (int kk = 0; kk < 2; kk++) {
      int kb = 4 * kk + 2 * h;
      i32x8 afp[2], bfv[2];
#pragma unroll
      for (int mr = 0; mr < 2; mr++) {
        int ii = mr * 32 + l31;
        i32x4 lo = *(const i32x4*)&Pp[kb * 1024 + ii * 16];
        i32x4 hi = *(const i32x4*)&Pp[(kb + 1) * 1024 + ii * 16];
        afp[mr] = __builtin_shufflevector(lo, hi, 0, 1, 2, 3, 4, 5, 6, 7);
      }
#pragma unroll
      for (int nr = 0; nr < 2; nr++) {
        int c = w * 64 + nr * 32 + l31;
        i32x4 lo = *(const i32x4*)&Vsm[kb * 8192 + c * 16];
        i32x4 hi = *(const i32x4*)&Vsm[(kb + 1) * 8192 + c * 16];
        bfv[nr] = __builtin_shufflevector(lo, hi, 0, 1, 2, 3, 4, 5, 6, 7);
      }
      __builtin_amdgcn_s_setprio(1);
#pragma unroll
      for (int mr = 0; mr < 2; mr++)
#pragma unroll
        for (int nr = 0; nr < 2; nr++)
          acc[mr][nr] = __builtin_amdgcn_mfma_scale_f32_32x32x64_f8f6f4(
              bfv[nr], afp[mr], acc[mr][nr], 0, 0, 0, 0x7F7F7F7F, 0, 0x7F7F7F7F);
      __builtin_amdgcn_s_setprio(0);
    }
  }

  // ---- epilogue: reduce rowsums across wj, divide, store H bf16 ----
  if (lane < 32) lsum[wj][wi * 32 + l31] = rsum;
  __syncthreads();
#pragma unroll
  for (int mr = 0; mr < 2; mr++) {
    int li = mr * 32 + l31;
    float lt = lsum[0][li] + lsum[1][li] + lsum[2][li] + lsum[3][li];
    float inv = 1.f / lt;
    long hrow = ((long)bz * NPOS + bm * 64 + li) * 512;
#pragma unroll
    for (int nr = 0; nr < 2; nr++) {
#pragma unroll
      for (int g = 0; g < 4; g++) {
        u16x4 o;
#pragma unroll
        for (int r = 0; r < 4; r++) o[r] = f2bf(acc[mr][nr][4 * g + r] * inv);
        *(u16x4*)&H[hrow + w * 64 + nr * 32 + 8 * g + 4 * h] = o;
      }
    }
  }
}

extern "C" void kernel_launch(void* const* d_in, const int* in_sizes, int n_in,
                              void* d_out, int out_size, void* d_ws, size_t ws_size,
                              hipStream_t stream) {
  const float* x     = (const float*)d_in[0];
  const float* gamma = (const float*)d_in[1];
  const float* beta  = (const float*)d_in[2];
  const float* wq = (const float*)d_in[3];
  const float* bq = (const float*)d_in[4];
  const float* wk = (const float*)d_in[5];
  const float* bk = (const float*)d_in[6];
  const float* wv = (const float*)d_in[7];
  const float* bv = (const float*)d_in[8];
  const float* wp = (const float*)d_in[9];
  const float* bp = (const float*)d_in[10];
  float* out = (float*)d_out;

  // workspace layout (bytes)
  char* W = (char*)d_ws;
  float* stats = (float*)(W + 0);               // 256 B
  u16* xnb  = (u16*)(W + 65792);                // 16,777,216 bf16 [b,c,p] residual
  u16* xnT  = (u16*)(W + 16843008);             // 16,777,216 bf16 [b,p,c]
  u16* wqkb = (u16*)(W + 33620224);             // 1,048,576  bf16 [1024(cq;ck)][512]
  u16* wvb  = (u16*)(W + 34668800);             // 524,288    bf16 [512][512]
  u16* wpb  = (u16*)(W + 35193088);             // 524,288    bf16 [512][512]
  u8*  QKf8 = (u8*)(W + 37290240);              // 16,777,216: Qf8 [b,p,512] | KT [b,32,4096,16]
  u8*  VT   = (u8*)(W + 54067456);              // 8,388,608 fp8 VT [b,256,512,16]
  u16* Hws  = (u16*)(W + 62456064);             // 16,777,216 bf16 [b,i,512]
  (void)in_sizes; (void)n_in; (void)out_size; (void)ws_size;

  hipMemsetAsync(W, 0, 256, stream);   // stats
  gn_partial<<<256, 256, 0, stream>>>(x, stats);
  norm_trans<<<dim3(64, 8, 4), 256, 0, stream>>>(x, stats, gamma, beta, xnb, xnT);
  cvt4<<<dim3(256, 4), 256, 0, stream>>>(wq, wk, wv, wp, wqkb, wqkb + 262144, wvb, wpb);

  const long NC = (long)NPOS * CDIM;    // 2,097,152
  const long CN = (long)CDIM * NPOS;
  const float scale = 0.044194173824159216f;        // 1/sqrt(512)
  const float scale2 = scale * 1.4426950408889634f; // 1/sqrt(512) * log2(e)

  // QK proj: A=xnT (M=16384), B=wqkb (N=1024), K=512. Q -> Qf8 rows, K -> KT planes.
  gemm_bt<0, 128><<<dim3(8, 128, 1), 256, 0, stream>>>(xnT, wqkb, QKf8, bq, bk, nullptr,
      1024, CDIM, CDIM, CDIM, 0, 0, 0, 0);
  // V proj: per batch M=512(c), N=4096(p), K=512 -> VT[b][p/16][c][16B]
  gemm_bt<5, 128><<<dim3(32, 4, 4), 256, 0, stream>>>(wvb, xnT, VT, bv, nullptr, nullptr,
      NPOS, CDIM, CDIM, CDIM, 0, NC, 0, 0);
  // fused attention: H[b,i,512] = softmax(Q.K^T/sqrt(c)) . V
  fattn<<<dim3(64, 1, NBATCH), 512, 0, stream>>>(QKf8, VT, Hws, scale2);
  // out[b][c, p] = wp . H_b^T + bp + xnb  (M=512, N=4096, K=512)
  gemm_bt<6, 128><<<dim3(32, 4, 4), 256, 0, stream>>>(wpb, Hws, (void*)out, bp, nullptr, xnb,
      NPOS, CDIM, CDIM, CDIM, 0, (long)NPOS * CDIM, CN, CN);
}

// Round 12
// 272.679 us; speedup vs baseline: 1.1238x; 1.0354x over previous
//
#include <hip/hip_runtime.h>
#include <hip/hip_bf16.h>

// AttnBlock: x[4,512,64,64] fp32. GroupNorm(8) -> qkv 1x1conv -> attn -> proj -> +xn
// Q,K,V,P fp8 e4m3. R17 = R16/R11 + COALESCED PRODUCER STORES (LDS bounce):
// R14's transposed KT/VT/Qf8 epilogues scattered 4B stores at 16-512B stride
// (gemm section regressed vs R0). Fix: bounce the packed fp8 C-tile through a
// 128x144-pitch LDS buffer (reuse Asm) and store 16B contiguous-lane words:
//   mode 0: Q rows (128B segments) / KT per-ch-plane contiguous p
//   mode 5: VT per-jc-plane contiguous c
// fattn: H epilogue bounced through dead Ksm/Vsm (single SMEM block) -> each
// wave stores one full 1KB row. Pure permutation changes - bit-identical math.

typedef unsigned short u16;
typedef unsigned char u8;
typedef __bf16 bf16x8 __attribute__((ext_vector_type(8)));
typedef float f32x4 __attribute__((ext_vector_type(4)));
typedef float f32x16 __attribute__((ext_vector_type(16)));
typedef int i32x4 __attribute__((ext_vector_type(4)));
typedef int i32x8 __attribute__((ext_vector_type(8)));
typedef unsigned short u16x4 __attribute__((ext_vector_type(4)));
typedef unsigned short u16x8 __attribute__((ext_vector_type(8)));

#define CDIM 512
#define NPOS 4096
#define NBATCH 4

__device__ __forceinline__ u16 f2bf(float x) {
  union { float f; unsigned u; } c; c.f = x;
  unsigned u = c.u;
  u += 0x7fffu + ((u >> 16) & 1u);   // round-to-nearest-even
  return (u16)(u >> 16);
}
__device__ __forceinline__ float bf2f(u16 h) {
  union { unsigned u; float f; } c; c.u = ((unsigned)h) << 16;
  return c.f;
}
// pack 4 floats -> 4 fp8 e4m3 bytes
__device__ __forceinline__ unsigned pk4_fp8(float a, float b, float c, float d) {
  unsigned v = __builtin_amdgcn_cvt_pk_fp8_f32(a, b, 0, false);
  v = __builtin_amdgcn_cvt_pk_fp8_f32(c, d, v, true);
  return v;
}

__device__ __forceinline__ void async16(const u16* g, u16* l) {
  __builtin_amdgcn_global_load_lds(
      (const __attribute__((address_space(1))) unsigned int*)g,
      (__attribute__((address_space(3))) unsigned int*)l, 16, 0, 0);
}
__device__ __forceinline__ void async16b(const u8* g, u8* l) {
  __builtin_amdgcn_global_load_lds(
      (const __attribute__((address_space(1))) unsigned int*)g,
      (__attribute__((address_space(3))) unsigned int*)l, 16, 0, 0);
}

__device__ __forceinline__ void drain_barrier() {
  asm volatile("s_waitcnt vmcnt(0)" ::: "memory");
  __builtin_amdgcn_s_barrier();
}

__device__ __forceinline__ float wred_sum(float v) {
#pragma unroll
  for (int o = 32; o > 0; o >>= 1) v += __shfl_xor(v, o, 64);
  return v;
}

// ---------------- GroupNorm stats: 32 (b,g) groups x 8 slices ----------------
__global__ __launch_bounds__(256) void gn_partial(const float* __restrict__ x,
                                                  float* __restrict__ stats) {
  int gidx = blockIdx.x >> 3;
  int slice = blockIdx.x & 7;
  const float4* src = (const float4*)x + (long)gidx * 65536 + (long)slice * 8192;
  float s = 0.f, ss = 0.f;
  for (int i = threadIdx.x; i < 8192; i += 256) {
    float4 v = src[i];
    s  += v.x + v.y + v.z + v.w;
    ss += v.x * v.x + v.y * v.y + v.z * v.z + v.w * v.w;
  }
  s = wred_sum(s); ss = wred_sum(ss);
  __shared__ float r1[4], r2[4];
  int lane = threadIdx.x & 63, wave = threadIdx.x >> 6;
  if (lane == 0) { r1[wave] = s; r2[wave] = ss; }
  __syncthreads();
  if (threadIdx.x == 0) {
    atomicAdd(&stats[gidx * 2 + 0], r1[0] + r1[1] + r1[2] + r1[3]);
    atomicAdd(&stats[gidx * 2 + 1], r2[0] + r2[1] + r2[2] + r2[3]);
  }
}

// ------- normalize + write xnb bf16 [b,c,p] (residual) and xnT bf16 [b,p,c] -------
// 64c x 64p tile, vectorized: float4 loads, u16x4 xnb stores, u16x8 xnT stores.
__global__ __launch_bounds__(256) void norm_trans(const float* __restrict__ x,
                                                  const float* __restrict__ stats,
                                                  const float* __restrict__ gamma,
                                                  const float* __restrict__ beta,
                                                  u16* __restrict__ xnb,
                                                  u16* __restrict__ xnT) {
  __shared__ float tile[64][65];
  int b = blockIdx.z, c0 = blockIdx.y * 64, p0 = blockIdx.x * 64;
  int g = (b << 3) + (c0 >> 6);
  float cnt = 1.f / 262144.f;
  float mu = stats[g * 2 + 0] * cnt;
  float ms = stats[g * 2 + 1] * cnt;
  float rstd = rsqrtf(ms - mu * mu + 1e-5f);
  int tq = threadIdx.x & 3, cl = threadIdx.x >> 2;   // cl: 0..63 (c row)
  int c = c0 + cl;
  float ga = gamma[c] * rstd, be = beta[c] - mu * ga;   // n = v*ga + be
  long rowb = ((long)(b * CDIM + c)) * NPOS + p0;
#pragma unroll
  for (int k = 0; k < 4; k++) {
    int pl = tq * 4 + k * 16;
    float4 v = *(const float4*)&x[rowb + pl];
    float4 n;
    n.x = v.x * ga + be; n.y = v.y * ga + be;
    n.z = v.z * ga + be; n.w = v.w * ga + be;
    u16x4 o; o[0] = f2bf(n.x); o[1] = f2bf(n.y); o[2] = f2bf(n.z); o[3] = f2bf(n.w);
    *(u16x4*)&xnb[rowb + pl] = o;
    tile[cl][pl] = n.x; tile[cl][pl + 1] = n.y;
    tile[cl][pl + 2] = n.z; tile[cl][pl + 3] = n.w;
  }
  __syncthreads();
  int pl = threadIdx.x >> 2;                          // p row 0..63
  long colb = ((long)(b * NPOS + p0 + pl)) * CDIM + c0;
#pragma unroll
  for (int s = 0; s < 2; s++) {
    int cc0 = (tq + 4 * s) * 8;
    u16x8 o;
#pragma unroll
    for (int e = 0; e < 8; e++) o[e] = f2bf(tile[cc0 + e][pl]);
    *(u16x8*)&xnT[colb + cc0] = o;
  }
}

// ------- fp32 -> bf16 weight convert (wq, wk, wv, wp all [512][512]), float4 -------
__global__ __launch_bounds__(256) void cvt4(const float* __restrict__ a, const float* __restrict__ b,
                                            const float* __restrict__ c, const float* __restrict__ d,
                                            u16* __restrict__ oa, u16* __restrict__ ob,
                                            u16* __restrict__ oc, u16* __restrict__ od) {
  int i = (blockIdx.x * 256 + threadIdx.x) * 4;
  const float* src; u16* dst;
  switch (blockIdx.y) {
    case 0: src = a; dst = oa; break;
    case 1: src = b; dst = ob; break;
    case 2: src = c; dst = oc; break;
    default: src = d; dst = od; break;
  }
  float4 v = *(const float4*)&src[i];
  u16x4 o; o[0] = f2bf(v.x); o[1] = f2bf(v.y); o[2] = f2bf(v.z); o[3] = f2bf(v.w);
  *(u16x4*)&dst[i] = o;
}

// ---------------- gemm_bt: C[m,n] = sum_k A[m,k]*B[n,k]  (both K-contig, bf16) ----------------
// 128(M) x BN tile, BK=64, BN/64*2 waves (wave tile 64x64), XOR-swizzled LDS, dbuf.
// MFMA operands SWAPPED: mfma(bfr, af, acc) -> C/D lane dim = m, reg dim = n.
// MODE 0: fp8 + bias; bn<4 -> Qf8 rows; bn>=4 -> KT[b][c'/16][p][16B]. LDS-bounce
//         epilogue -> 16B contiguous-lane stores.
// MODE 5: fp8 + bias[m] -> VT[b][p/16][c][16B]. LDS-bounce epilogue.
// MODE 6: f32 out = acc + bias[m] + bf16 resid (proj + residual), direct f32x4.
template <int MODE, int BN>
__global__ __launch_bounds__(BN * 2, 2) void gemm_bt(
    const u16* __restrict__ A, const u16* __restrict__ B,
    void* __restrict__ Cp, const float* __restrict__ bias,
    const float* __restrict__ bias1, const u16* __restrict__ residb,
    int N, int K, int lda, int ldb,
    long sA, long sB, long sC, long sR) {
  __shared__ u16 Asm[2][128 * 64];
  __shared__ u16 Bsm[2][BN * 64];
  constexpr int NT = BN * 2;       // threads
  constexpr int STEP = NT / 8;     // staging rows per round
  int bz = blockIdx.z;
  A += (long)bz * sA;
  B += (long)bz * sB;
  int bm = blockIdx.y, bn = blockIdx.x;
  int tid = threadIdx.x;
  int lane = tid & 63, wave = tid >> 6;
  int wm = (wave & 1) * 64, wn = (wave >> 1) * 64;

  int row0 = tid >> 3;             // 0..STEP-1
  int ko = (tid & 7) * 8;
  int kos = ko ^ ((row0 & 7) * 8); // STEP multiple of 8 -> row&7 invariant
  f32x4 acc[4][4] = {};
  int row16 = lane & 15;
  int kq = (lane >> 4) * 8;

  auto stage = [&](int buf, int k0) {
#pragma unroll
    for (int r = 0; r < 128 / STEP; r++) {
      int row = row0 + r * STEP;
      async16(A + (long)(bm * 128 + row) * lda + k0 + kos, &Asm[buf][row * 64 + ko]);
    }
#pragma unroll
    for (int r = 0; r < BN / STEP; r++) {
      int row = row0 + r * STEP;
      async16(B + (long)(bn * BN + row) * ldb + k0 + kos, &Bsm[buf][row * 64 + ko]);
    }
  };

  stage(0, 0);
  drain_barrier();
  int cur = 0;
  for (int k0 = 0; k0 < K; k0 += 64) {
    if (k0 + 64 < K) stage(cur ^ 1, k0 + 64);   // prefetch next tile
#pragma unroll
    for (int s2 = 0; s2 < 2; s2++) {
      bf16x8 af[4], bfr[4];
#pragma unroll
      for (int i = 0; i < 4; i++) {
        int row = wm + i * 16 + row16;
        af[i] = *(const bf16x8*)&Asm[cur][row * 64 + ((s2 * 32 + kq) ^ ((row & 7) * 8))];
      }
#pragma unroll
      for (int j = 0; j < 4; j++) {
        int row = wn + j * 16 + row16;
        bfr[j] = *(const bf16x8*)&Bsm[cur][row * 64 + ((s2 * 32 + kq) ^ ((row & 7) * 8))];
      }
      __builtin_amdgcn_s_setprio(1);
#pragma unroll
      for (int i = 0; i < 4; i++)
#pragma unroll
        for (int j = 0; j < 4; j++)
          acc[i][j] = __builtin_amdgcn_mfma_f32_16x16x32_bf16(bfr[j], af[i], acc[i][j], 0, 0, 0);
      __builtin_amdgcn_s_setprio(0);
    }
    drain_barrier();
    cur ^= 1;
  }

  // epilogue (swapped layout): m = lane&15 within tile, n = (lane>>4)*4 + reg
  int mcol = lane & 15, rb = (lane >> 4) * 4;

  if constexpr (MODE == 0) {
    // bounce packed fp8 tile through LDS (pitch 144), then coalesced 16B stores
    u8* Clb = (u8*)&Asm[0][0];   // 128 x 144 = 18432 B <= 32768
#pragma unroll
    for (int i = 0; i < 4; i++) {
      int lm = wm + i * 16 + mcol;
#pragma unroll
      for (int j = 0; j < 4; j++) {
        int ln = wn + j * 16 + rb;
        int gn0 = bn * BN + ln;
        const float* bb = (gn0 < 512) ? (bias + gn0) : (bias1 + (gn0 - 512));
        float v[4];
#pragma unroll
        for (int r = 0; r < 4; r++) v[r] = acc[i][j][r] + bb[r];
        *(unsigned*)&Clb[lm * 144 + ln] = pk4_fp8(v[0], v[1], v[2], v[3]);
      }
    }
    __syncthreads();
    if (bn * BN < 512) {
      // Q region: Qf8[gm][c] rows; lanes vary c16 fast -> 128B segments
#pragma unroll
      for (int r = 0; r < 4; r++) {
        int z = tid + r * NT;
        int pl = z >> 3, c16 = z & 7;
        i32x4 v = *(const i32x4*)&Clb[pl * 144 + c16 * 16];
        *(i32x4*)&((u8*)Cp)[(long)(bm * 128 + pl) * 512 + bn * BN + c16 * 16] = v;
      }
    } else {
      // K region: KT[b][ch][p][16B]; lanes vary p fast -> contiguous per plane
      int cb = bn * BN - 512;
#pragma unroll
      for (int r = 0; r < 4; r++) {
        int z = tid + r * NT;
        int ch = z >> 7, pl = z & 127;
        int gm = bm * 128 + pl;
        int b = gm >> 12, p = gm & 4095;
        i32x4 v = *(const i32x4*)&Clb[pl * 144 + ch * 16];
        *(i32x4*)&((u8*)Cp)[8388608L + (long)b * 2097152 +
                            (long)((cb >> 4) + ch) * 65536 + p * 16] = v;
      }
    }
    return;
  }

  if constexpr (MODE == 5) {
    // bounce: Clb[c_local][p_local]; VT word = 16 consecutive p at fixed c
    u8* Clb = (u8*)&Asm[0][0];
#pragma unroll
    for (int i = 0; i < 4; i++) {
      int lm = wm + i * 16 + mcol;            // c_local
      float bm_add = bias[bm * 128 + lm];
#pragma unroll
      for (int j = 0; j < 4; j++) {
        int ln = wn + j * 16 + rb;            // p_local
        float v[4];
#pragma unroll
        for (int r = 0; r < 4; r++) v[r] = acc[i][j][r] + bm_add;
        *(unsigned*)&Clb[lm * 144 + ln] = pk4_fp8(v[0], v[1], v[2], v[3]);
      }
    }
    __syncthreads();
#pragma unroll
    for (int r = 0; r < 4; r++) {
      int z = tid + r * NT;
      int jc = z >> 7, cl = z & 127;
      i32x4 v = *(const i32x4*)&Clb[cl * 144 + jc * 16];
      *(i32x4*)&((u8*)Cp)[(long)bz * 2097152 + (long)(bn * 8 + jc) * 8192 +
                          (bm * 128 + cl) * 16] = v;
    }
    return;
  }

  if constexpr (MODE == 6) {
    long zC = (long)bz * sC;
#pragma unroll
    for (int i = 0; i < 4; i++) {
      int gm = bm * 128 + wm + i * 16 + mcol;
      float bm_add = bias[gm];
#pragma unroll
      for (int j = 0; j < 4; j++) {
        int gn0 = bn * BN + wn + j * 16 + rb;
        long off = zC + (long)gm * N + gn0;
        u16x4 rv = *(const u16x4*)&residb[(long)bz * sR + (long)gm * N + gn0];
        f32x4 o;
#pragma unroll
        for (int r = 0; r < 4; r++) o[r] = acc[i][j][r] + bm_add + bf2f(rv[r]);
        *(f32x4*)&((float*)Cp)[off] = o;
      }
    }
  }
}

// ---------------- fattn: fused S=exp(QK^T*scale) and H=(S.V)/rowsum ----------------
// 256 blocks (XCD-swizzled: 2 XCDs per batch), 512 thr (8 waves: wi=w>>2, wj=w&3).
// i-tile 64, j-step 128, 32 steps. MX-fp8 MFMA 32x32x64, swapped operands
// (D lane=m(l31), reg n=(r&3)+8*(r>>2)+4*h; A/B frag: lane=row, k-bytes h*32..+31).
// CHUNK-MAJOR LDS (R9-verified conflict-free) from TRANSPOSED global buffers.
// Per step (R3 schedule): syncA; stageV(t); S=Q.K (8 MFMA); exp2 -> P + rowsum;
// syncB; stageK(t+1); acc += P.V^T (8 MFMA).
// Epilogue: lsum reduce, H=(PV)/l -> LDS bounce (dead K/V region) -> coalesced
// 1KB-row stores.
__global__ __launch_bounds__(512, 1) void fattn(const u8* __restrict__ Qf8,
                                                const u8* __restrict__ VT,
                                                u16* __restrict__ H, float scale2) {
  __shared__ u8 SMEM[139264];    // [0,64K) Ksm | [64K,128K) Vsm | [128K,+8K) Pp
  __shared__ float lsum[4][64];
  u8* Ksm = SMEM;
  u8* Vsm = SMEM + 65536;
  u8* Pp  = SMEM + 131072;
  int tid = threadIdx.x, lane = tid & 63, w = tid >> 6;
  int l31 = lane & 31, h = lane >> 5;
  int wi = w >> 2, wj = w & 3;
  // XCD swizzle (R7-verified): round-robin dispatch -> xcd = lid&7; 2 XCDs/batch.
  int lid = blockIdx.x + 64 * blockIdx.z;
  int xcd = lid & 7, slot = lid >> 3;
  int bz = xcd >> 1;
  int bm = (xcd & 1) * 32 + slot;
  const u8* Qb  = Qf8 + (long)bz * 2097152;            // [4096 p][512 c]
  const u8* KTb = Qf8 + 8388608 + (long)bz * 2097152;  // [32 ch][4096 p][16B]
  const u8* VTb = VT + (long)bz * 2097152;             // [256 jc][512 c][16B]

  // Q rows (bm*64 + wi*32 + l31), full c=512, resident in regs (64 VGPR)
  i32x8 qf[8];
  {
    const u8* qrow = Qb + (long)(bm * 64 + wi * 32 + l31) * 512 + h * 32;
#pragma unroll
    for (int s = 0; s < 8; s++) {
      i32x4 lo = *(const i32x4*)(qrow + s * 64);
      i32x4 hi = *(const i32x4*)(qrow + s * 64 + 16);
      qf[s] = __builtin_shufflevector(lo, hi, 0, 1, 2, 3, 4, 5, 6, 7);
    }
  }

  // stage K(t): zz -> ch = zz>>7, j = zz&127; LDS linear; global contiguous in j
  auto stageK = [&](int t) {
#pragma unroll
    for (int r = 0; r < 8; r++) {
      int zz = tid + r * 512;
      int ch = zz >> 7, j = zz & 127;
      async16b(KTb + (long)ch * 65536 + (t * 128 + j) * 16, &Ksm[zz * 16]);
    }
  };
  // stage V(t): zz -> jc = zz>>9, c = zz&511; global contiguous in c
  auto stageV = [&](int t) {
#pragma unroll
    for (int r = 0; r < 8; r++) {
      int zz = tid + r * 512;
      int jc = zz >> 9, c = zz & 511;
      async16b(VTb + (long)(t * 8 + jc) * 8192 + c * 16, &Vsm[zz * 16]);
    }
  };

  f32x16 acc[2][2] = {};   // [i-sub][c-sub]; wave c-base = w*64
  float rsum = 0.f;
  int i = wi * 32 + l31;   // this wave's S row (lane)
  int jr = wj * 32 + l31;  // this wave's K row (lane)

  stageK(0);

  for (int t = 0; t < 32; t++) {
    __syncthreads();              // A: K(t) staged+drained; Vsm/Pp reads of t-1 done
    stageV(t);
    // ---- phase 1: S = Q.K^T over c=512 (8 MFMA, regs + Ksm) ----
    f32x16 s16 = {};
#pragma unroll
    for (int s = 0; s < 8; s++) {
      int a0 = (4 * s + 2 * h) * 2048 + jr * 16;
      i32x4 lo = *(const i32x4*)&Ksm[a0];
      i32x4 hi = *(const i32x4*)&Ksm[a0 + 2048];
      i32x8 bfk = __builtin_shufflevector(lo, hi, 0, 1, 2, 3, 4, 5, 6, 7);
      __builtin_amdgcn_s_setprio(1);
      s16 = __builtin_amdgcn_mfma_scale_f32_32x32x64_f8f6f4(
          bfk, qf[s], s16, 0, 0, 0, 0x7F7F7F7F, 0, 0x7F7F7F7F);
      __builtin_amdgcn_s_setprio(0);
    }
    // exp2 + rowsum + pack P -> Pp chunk-major (reg r: j = wj*32+(r&3)+8*(r>>2)+4h)
    {
      float pv[16];
      float rs = 0.f;
#pragma unroll
      for (int r = 0; r < 16; r++) { pv[r] = exp2f(s16[r] * scale2); rs += pv[r]; }
      rsum += rs + __shfl_xor(rs, 32, 64);
#pragma unroll
      for (int g = 0; g < 4; g++) {
        int jc = wj * 2 + (g >> 1);
        *(unsigned*)&Pp[jc * 1024 + i * 16 + 8 * (g & 1) + 4 * h] =
            pk4_fp8(pv[4 * g], pv[4 * g + 1], pv[4 * g + 2], pv[4 * g + 3]);
      }
    }
    __syncthreads();              // B: V(t) staged+drained; Pp writes visible
    if (t < 31) stageK(t + 1);
    // ---- phase 2: acc += P.V^T over local j=128 (2 MFMA k-steps) ----
#pragma unroll
    for (int kk = 0; kk < 2; kk++) {
      int kb = 4 * kk + 2 * h;
      i32x8 afp[2], bfv[2];
#pragma unroll
      for (int mr = 0; mr < 2; mr++) {
        int ii = mr * 32 + l31;
        i32x4 lo = *(const i32x4*)&Pp[kb * 1024 + ii * 16];
        i32x4 hi = *(const i32x4*)&Pp[(kb + 1) * 1024 + ii * 16];
        afp[mr] = __builtin_shufflevector(lo, hi, 0, 1, 2, 3, 4, 5, 6, 7);
      }
#pragma unroll
      for (int nr = 0; nr < 2; nr++) {
        int c = w * 64 + nr * 32 + l31;
        i32x4 lo = *(const i32x4*)&Vsm[kb * 8192 + c * 16];
        i32x4 hi = *(const i32x4*)&Vsm[(kb + 1) * 8192 + c * 16];
        bfv[nr] = __builtin_shufflevector(lo, hi, 0, 1, 2, 3, 4, 5, 6, 7);
      }
      __builtin_amdgcn_s_setprio(1);
#pragma unroll
      for (int mr = 0; mr < 2; mr++)
#pragma unroll
        for (int nr = 0; nr < 2; nr++)
          acc[mr][nr] = __builtin_amdgcn_mfma_scale_f32_32x32x64_f8f6f4(
              bfv[nr], afp[mr], acc[mr][nr], 0, 0, 0, 0x7F7F7F7F, 0, 0x7F7F7F7F);
      __builtin_amdgcn_s_setprio(0);
    }
  }

  // ---- epilogue: reduce rowsums across wj, divide, bounce H via LDS, store ----
  if (lane < 32) lsum[wj][wi * 32 + l31] = rsum;
  __syncthreads();                // also: all Ksm/Vsm/Pp traffic complete
  u16* Hl = (u16*)SMEM;           // 64 rows x pitch 520 u16 (1040 B) = 66560 B
#pragma unroll
  for (int mr = 0; mr < 2; mr++) {
    int li = mr * 32 + l31;
    float lt = lsum[0][li] + lsum[1][li] + lsum[2][li] + lsum[3][li];
    float inv = 1.f / lt;
#pragma unroll
    for (int nr = 0; nr < 2; nr++) {
#pragma unroll
      for (int g = 0; g < 4; g++) {
        u16x4 o;
#pragma unroll
        for (int r = 0; r < 4; r++) o[r] = f2bf(acc[mr][nr][4 * g + r] * inv);
        *(u16x4*)&Hl[li * 520 + w * 64 + nr * 32 + 8 * g + 4 * h] = o;
      }
    }
  }
  __syncthreads();
#pragma unroll
  for (int r = 0; r < 8; r++) {
    int z = tid + r * 512;
    int row = z >> 6, c16 = z & 63;
    i32x4 v = *(const i32x4*)&Hl[row * 520 + c16 * 8];
    *(i32x4*)&H[((long)bz * NPOS + bm * 64 + row) * 512 + c16 * 8] = v;
  }
}

extern "C" void kernel_launch(void* const* d_in, const int* in_sizes, int n_in,
                              void* d_out, int out_size, void* d_ws, size_t ws_size,
                              hipStream_t stream) {
  const float* x     = (const float*)d_in[0];
  const float* gamma = (const float*)d_in[1];
  const float* beta  = (const float*)d_in[2];
  const float* wq = (const float*)d_in[3];
  const float* bq = (const float*)d_in[4];
  const float* wk = (const float*)d_in[5];
  const float* bk = (const float*)d_in[6];
  const float* wv = (const float*)d_in[7];
  const float* bv = (const float*)d_in[8];
  const float* wp = (const float*)d_in[9];
  const float* bp = (const float*)d_in[10];
  float* out = (float*)d_out;

  // workspace layout (bytes)
  char* W = (char*)d_ws;
  float* stats = (float*)(W + 0);               // 256 B
  u16* xnb  = (u16*)(W + 65792);                // 16,777,216 bf16 [b,c,p] residual
  u16* xnT  = (u16*)(W + 16843008);             // 16,777,216 bf16 [b,p,c]
  u16* wqkb = (u16*)(W + 33620224);             // 1,048,576  bf16 [1024(cq;ck)][512]
  u16* wvb  = (u16*)(W + 34668800);             // 524,288    bf16 [512][512]
  u16* wpb  = (u16*)(W + 35193088);             // 524,288    bf16 [512][512]
  u8*  QKf8 = (u8*)(W + 37290240);              // 16,777,216: Qf8 [b,p,512] | KT [b,32,4096,16]
  u8*  VT   = (u8*)(W + 54067456);              // 8,388,608 fp8 VT [b,256,512,16]
  u16* Hws  = (u16*)(W + 62456064);             // 16,777,216 bf16 [b,i,512]
  (void)in_sizes; (void)n_in; (void)out_size; (void)ws_size;

  hipMemsetAsync(W, 0, 256, stream);   // stats
  gn_partial<<<256, 256, 0, stream>>>(x, stats);
  norm_trans<<<dim3(64, 8, 4), 256, 0, stream>>>(x, stats, gamma, beta, xnb, xnT);
  cvt4<<<dim3(256, 4), 256, 0, stream>>>(wq, wk, wv, wp, wqkb, wqkb + 262144, wvb, wpb);

  const long NC = (long)NPOS * CDIM;    // 2,097,152
  const long CN = (long)CDIM * NPOS;
  const float scale = 0.044194173824159216f;        // 1/sqrt(512)
  const float scale2 = scale * 1.4426950408889634f; // 1/sqrt(512) * log2(e)

  // QK proj: A=xnT (M=16384), B=wqkb (N=1024), K=512. Q -> Qf8 rows, K -> KT planes.
  gemm_bt<0, 128><<<dim3(8, 128, 1), 256, 0, stream>>>(xnT, wqkb, QKf8, bq, bk, nullptr,
      1024, CDIM, CDIM, CDIM, 0, 0, 0, 0);
  // V proj: per batch M=512(c), N=4096(p), K=512 -> VT[b][p/16][c][16B]
  gemm_bt<5, 128><<<dim3(32, 4, 4), 256, 0, stream>>>(wvb, xnT, VT, bv, nullptr, nullptr,
      NPOS, CDIM, CDIM, CDIM, 0, NC, 0, 0);
  // fused attention: H[b,i,512] = softmax(Q.K^T/sqrt(c)) . V
  fattn<<<dim3(64, 1, NBATCH), 512, 0, stream>>>(QKf8, VT, Hws, scale2);
  // out[b][c, p] = wp . H_b^T + bp + xnb  (M=512, N=4096, K=512)
  gemm_bt<6, 128><<<dim3(32, 4, 4), 256, 0, stream>>>(wpb, Hws, (void*)out, bp, nullptr, xnb,
      NPOS, CDIM, CDIM, CDIM, 0, (long)NPOS * CDIM, CN, CN);
}